// Round 10
// baseline (159.871 us; speedup 1.0000x reference)
//
#include <hip/hip_runtime.h>
#include <hip/hip_bf16.h>

// Problem constants (fixed by setup_inputs)
#define NB 4
#define SEQ 2048
#define HID 768
#define NSPAN 16384            // spans per batch
#define M_TOT (NB * NSPAN)     // 65536 rows
#define K2 1536                // 2*HID
#define MROWS (NB * 3 * SEQ)   // 24576 table rows (batch x width-class x pos)
#define NT12 12                // HID / 64 K-tiles
// old (fallback) path constants
#define CMP_CAP 66560
#define MT_TOT 520
#define NWG_OLD (MT_TOT * 6)
// new path GEMM grid: 96 m-tiles (BM=256) x 12 n-strips (BN=128)
#define NWG_NEW 1152

typedef float f32x4 __attribute__((ext_vector_type(4)));
typedef short s16x8 __attribute__((ext_vector_type(8)));
typedef unsigned short u16x4 __attribute__((ext_vector_type(4)));
using bf16 = __hip_bfloat16;

__device__ __forceinline__ void gll16(const void* g, void* l) {
    __builtin_amdgcn_global_load_lds(
        (const __attribute__((address_space(1))) unsigned*)g,
        (__attribute__((address_space(3))) unsigned*)l, 16, 0, 0);
}

__device__ __forceinline__ float bf2f(unsigned short v) {
    union { unsigned u; float f; } cv; cv.u = ((unsigned)v) << 16; return cv.f;
}

// ---------------------------------------------------------------------------
__global__ void mask_detect_kernel(const unsigned* __restrict__ masks, int* __restrict__ flag) {
    int t = blockIdx.x * 256 + threadIdx.x;
    if (t < 16384) {
        unsigned v = masks[t];
        if (v > 1u) atomicOr(flag, 1);   // multi-byte pattern => byte-packed bools
    }
}

__device__ __forceinline__ bool mask_at(const int* masks, int u8, int m) {
    return u8 ? (((const unsigned char*)masks)[m] != 0) : (masks[m] != 0);
}

// ---------------------------------------------------------------------------
// M3[b][c][p][h] = max over T[b, p .. p+c] (c = 0,1,2 => window 1,2,3), bf16.
__global__ void prep_m3_kernel(const float* __restrict__ T, bf16* __restrict__ M3) {
    int b = blockIdx.y;
    int p0 = blockIdx.x * 16;
    int t = threadIdx.x;   // 256
    const float* Tb = T + (size_t)b * SEQ * HID;
    bf16* o0 = M3 + (size_t)(b * 3 + 0) * SEQ * HID;
    bf16* o1 = M3 + (size_t)(b * 3 + 1) * SEQ * HID;
    bf16* o2 = M3 + (size_t)(b * 3 + 2) * SEQ * HID;
#pragma unroll
    for (int c = 0; c < 3; ++c) {
        int h = t + c * 256;
        float x0 = Tb[(size_t)p0 * HID + h];
        float x1 = Tb[(size_t)min(p0 + 1, SEQ - 1) * HID + h];
        for (int i = 0; i < 16; ++i) {
            int p = p0 + i;
            float x2 = Tb[(size_t)min(p + 2, SEQ - 1) * HID + h];
            float m2 = fmaxf(x0, x1);
            float m3v = fmaxf(m2, x2);
            size_t off = (size_t)p * HID + h;
            o0[off] = __float2bfloat16(x0);
            o1[off] = __float2bfloat16(m2);
            o2[off] = __float2bfloat16(m3v);
            x0 = x1; x1 = x2;
        }
    }
}

// ===========================================================================
// NEW PATH: dense table GEMM + gather-add epilogue
// ===========================================================================

// Wt2[n'][k'] (n' 0..1535, k' 0..767):
//   n'<768:  W[k'][n']         (start half, W rows 0..767)
//   n'>=768: W[768+k'][n'-768] (end half,  W rows 768..1535)
__global__ void prep_wt2_kernel(const float* __restrict__ W, bf16* __restrict__ Wt) {
    __shared__ float tile[64][65];
    int k0 = blockIdx.x * 64;          // 12 blocks
    int n0 = blockIdx.y * 64;          // 24 blocks
    int half = (n0 >= HID) ? 1 : 0;
    int nn = n0 - half * HID;
    int t = threadIdx.x;
    int c = t & 63, r4 = t >> 6;
    for (int r = r4; r < 64; r += 4)
        tile[r][c] = W[(size_t)(half * HID + k0 + r) * HID + nn + c];
    __syncthreads();
    for (int r = r4; r < 64; r += 4)
        Wt[(size_t)(n0 + r) * HID + k0 + c] = __float2bfloat16(tile[c][r]);
}

// Dense phase-pipelined GEMM: P[r][n'] = sum_k M3[r][k] * Wt2[n'][k].
// BM=256 x BN=128, 512 thr = 8 waves (4m x 2n, 64x64 out each), BK=64,
// 12 K-tiles. LDS 128KB: A 3-buf rotation (3x32KB @0), B 2-buf (2x16KB @96K).
// Per tile t, two phases:
//  p0: vmcnt(6|0); barrier; ST_A(t+2); ds_read B(all 8) + A frags 0,1;
//      setprio(1); 16 MFMA; setprio(0)
//  p1: barrier; ST_B(t+2); ds_read A frags 2,3; setprio(1); 16 MFMA; setprio(0)
// Deadness: ST_A(t+2) hits Abuf[(t-1)%3] (last read p1(t-1), behind p0's
// barrier); ST_B(t+2) hits Bbuf[t&1] (last read p0(t), behind p1's barrier).
// vmcnt: per-thread issue order ... A(t+1)[4]@p0(t), B(t+1)[2]@p1(t) => at
// p0(t) the 6 newest outstanding are A(t+1),B(t+1) => vmcnt(6); last tile 0.
// chunk^=row&7 swizzle on source AND read (proven 0-conflict pattern).
__global__ __launch_bounds__(512, 1)
void dense_gemm_kernel(const bf16* __restrict__ M3, const bf16* __restrict__ Wt,
                       bf16* __restrict__ P) {
    __shared__ char lds[131072];

    const int tid = threadIdx.x;
    const int x = blockIdx.x;
    // XCD co-location (R8-proven, balanced): 12 n-strips of one mt on one XCD.
    const int g = x & 7, j = x >> 3;
    const int mt = (j / 12) * 8 + g;   // 0..95, bijective
    const int ns = j % 12;             // 0..11
    const int m0 = mt * 256, n0 = ns * 128;

    const int lane = tid & 63, w = tid >> 6;
    const int wm = w >> 1, wn = w & 1;        // 4m x 2n wave grid
    const int lr = lane & 15, lg = lane >> 4;

    // Stage geometry: issue = 64 rows x 128B = 8KB; wave w covers rows
    // [w*8, w*8+8) of the issue (lane>>3 = row, lane&7 = chunk, XOR row&7).
    const int srow_w = w * 8 + (lane >> 3);
    const int swz = ((lane & 7) ^ ((lane >> 3) & 7)) << 4;
    const char* aSrc[4];
    const char* bSrc[2];
#pragma unroll
    for (int q = 0; q < 4; ++q)
        aSrc[q] = (const char*)M3 + (size_t)(m0 + q * 64 + srow_w) * (HID * 2) + swz;
#pragma unroll
    for (int q = 0; q < 2; ++q)
        bSrc[q] = (const char*)Wt + (size_t)(n0 + q * 64 + srow_w) * (HID * 2) + swz;
    const int dstOff = w * 1024;

#define ST_A(T) do { char* _b = lds + ((T) % 3) * 32768; const int _c = (T) * 128; \
        gll16(aSrc[0] + _c, _b + 0 * 8192 + dstOff); \
        gll16(aSrc[1] + _c, _b + 1 * 8192 + dstOff); \
        gll16(aSrc[2] + _c, _b + 2 * 8192 + dstOff); \
        gll16(aSrc[3] + _c, _b + 3 * 8192 + dstOff); } while (0)
#define ST_B(T) do { char* _b = lds + 98304 + ((T) & 1) * 16384; const int _c = (T) * 128; \
        gll16(bSrc[0] + _c, _b + 0 * 8192 + dstOff); \
        gll16(bSrc[1] + _c, _b + 1 * 8192 + dstOff); } while (0)
#define FENCE_BAR() do { __builtin_amdgcn_sched_barrier(0); \
        __builtin_amdgcn_s_barrier(); \
        __builtin_amdgcn_sched_barrier(0); } while (0)

    f32x4 acc[4][4];
#pragma unroll
    for (int i = 0; i < 4; i++)
#pragma unroll
        for (int j2 = 0; j2 < 4; j2++) acc[i][j2] = (f32x4){0.f, 0.f, 0.f, 0.f};

    // Prologue: A0,B0,A1,B1 (12 loads/thread in flight).
    ST_A(0); ST_B(0); ST_A(1); ST_B(1);

    for (int t = 0; t < NT12; ++t) {
        const char* Ab = lds + (t % 3) * 32768;
        const char* Bb = lds + 98304 + (t & 1) * 16384;
        s16x8 bfr[4][2];

        // ---- phase 0 ----
        if (t < NT12 - 1) { asm volatile("s_waitcnt vmcnt(6)" ::: "memory"); }
        else              { asm volatile("s_waitcnt vmcnt(0)" ::: "memory"); }
        FENCE_BAR();
        if (t + 2 < NT12) ST_A(t + 2);
#pragma unroll
        for (int jf = 0; jf < 4; ++jf) {
            int row = wn * 64 + jf * 16 + lr;
#pragma unroll
            for (int ks = 0; ks < 2; ++ks)
                bfr[jf][ks] = *(const s16x8*)(Bb + row * 128 + ((((ks << 2) | lg) ^ (row & 7)) << 4));
        }
        {
            s16x8 af[2][2];
#pragma unroll
            for (int i = 0; i < 2; ++i) {
                int row = wm * 64 + i * 16 + lr;
#pragma unroll
                for (int ks = 0; ks < 2; ++ks)
                    af[i][ks] = *(const s16x8*)(Ab + row * 128 + ((((ks << 2) | lg) ^ (row & 7)) << 4));
            }
            __builtin_amdgcn_s_setprio(1);
#pragma unroll
            for (int ks = 0; ks < 2; ++ks)
#pragma unroll
                for (int i = 0; i < 2; ++i)
#pragma unroll
                    for (int jf = 0; jf < 4; ++jf)
                        acc[i][jf] = __builtin_amdgcn_mfma_f32_16x16x32_bf16(af[i][ks], bfr[jf][ks], acc[i][jf], 0, 0, 0);
            __builtin_amdgcn_s_setprio(0);
        }

        // ---- phase 1 ----
        FENCE_BAR();
        if (t + 2 < NT12) ST_B(t + 2);
        {
            s16x8 af[2][2];
#pragma unroll
            for (int i = 0; i < 2; ++i) {
                int row = wm * 64 + (i + 2) * 16 + lr;
#pragma unroll
                for (int ks = 0; ks < 2; ++ks)
                    af[i][ks] = *(const s16x8*)(Ab + row * 128 + ((((ks << 2) | lg) ^ (row & 7)) << 4));
            }
            __builtin_amdgcn_s_setprio(1);
#pragma unroll
            for (int ks = 0; ks < 2; ++ks)
#pragma unroll
                for (int i = 0; i < 2; ++i)
#pragma unroll
                    for (int jf = 0; jf < 4; ++jf)
                        acc[i + 2][jf] = __builtin_amdgcn_mfma_f32_16x16x32_bf16(af[i][ks], bfr[jf][ks], acc[i + 2][jf], 0, 0, 0);
            __builtin_amdgcn_s_setprio(0);
        }
    }
#undef ST_A
#undef ST_B
#undef FENCE_BAR

    // C/D layout (verified m89): col = lane&15, row = (lane>>4)*4 + q
    unsigned short* Pu = (unsigned short*)P;
#pragma unroll
    for (int i = 0; i < 4; i++) {
#pragma unroll
        for (int j2 = 0; j2 < 4; j2++) {
#pragma unroll
            for (int q = 0; q < 4; q++) {
                int prow = m0 + wm * 64 + i * 16 + lg * 4 + q;
                int pcol = n0 + wn * 64 + j2 * 16 + lr;
                bf16 v = __float2bfloat16(acc[i][j2][q]);
                Pu[(size_t)prow * K2 + pcol] = *(unsigned short*)&v;
            }
        }
    }
}

// out[m] = mask ? P[rS][0:768] + P[rE][768:1536] + bias : bias
__global__ __launch_bounds__(256)
void epilogue_kernel(const bf16* __restrict__ P, const int* __restrict__ span_ids,
                     const int* __restrict__ masks, const int* __restrict__ flag,
                     const int* __restrict__ pooling, const float* __restrict__ bias,
                     float* __restrict__ out) {
    int gw = (blockIdx.x * 256 + threadIdx.x) >> 6;   // 0..8191
    int lane = threadIdx.x & 63;
    int u8 = flag[0];
    int window = (pooling[0] != 0) ? 1 : 3;
    const unsigned short* Pu = (const unsigned short*)P;
    for (int m = gw; m < M_TOT; m += 8192) {
        float* orow = out + (size_t)m * HID;
        if (!mask_at(masks, u8, m)) {
#pragma unroll
            for (int rnd = 0; rnd < 3; ++rnd) {
                int n = rnd * 256 + lane * 4;
                *(f32x4*)(orow + n) = *(const f32x4*)(bias + n);
            }
            continue;
        }
        int s = span_ids[2 * m], e = span_ids[2 * m + 1];
        int b = m >> 14;
        int cw = min(window, e - s);           // e-s >= 1 always
        int base = (b * 3 + (cw - 1)) * SEQ;
        const unsigned short* ps = Pu + (size_t)(base + s) * K2;
        const unsigned short* pe = Pu + (size_t)(base + e - cw) * K2 + HID;
#pragma unroll
        for (int rnd = 0; rnd < 3; ++rnd) {
            int n = rnd * 256 + lane * 4;
            u16x4 a = *(const u16x4*)(ps + n);
            u16x4 c = *(const u16x4*)(pe + n);
            f32x4 bb = *(const f32x4*)(bias + n);
            f32x4 r;
#pragma unroll
            for (int k = 0; k < 4; ++k) r[k] = bf2f(a[k]) + bf2f(c[k]) + bb[k];
            *(f32x4*)(orow + n) = r;
        }
    }
}

// ===========================================================================
// OLD PATH (fallback if ws_size too small): R8's compacted gathered GEMM
// ===========================================================================

__global__ void init_compact_kernel(int* __restrict__ cS, int* __restrict__ cE,
                                    int* __restrict__ cO) {
    int i = blockIdx.x * 256 + threadIdx.x;
    if (i < CMP_CAP) { cS[i] = 0; cE[i] = 0; cO[i] = -1; }
}

__global__ void count_kernel(const int* __restrict__ masks, const int* __restrict__ flag,
                             int* __restrict__ blockCnt) {
    int bid = blockIdx.x, tid = threadIdx.x;
    bool act = mask_at(masks, flag[0], bid * 256 + tid);
    unsigned long long b = __ballot(act);
    __shared__ int wc[4];
    if ((tid & 63) == 0) wc[tid >> 6] = __popcll(b);
    __syncthreads();
    if (tid == 0) blockCnt[bid] = wc[0] + wc[1] + wc[2] + wc[3];
}

__global__ void scan_kernel(const int* __restrict__ blockCnt, int* __restrict__ blockOff,
                            int* __restrict__ cnt) {
    __shared__ int s[256];
    int t = threadIdx.x;
    int mine = blockCnt[t];
    s[t] = mine;
    __syncthreads();
    for (int d = 1; d < 256; d <<= 1) {
        int v = (t >= d) ? s[t - d] : 0;
        __syncthreads();
        s[t] += v;
        __syncthreads();
    }
    blockOff[t] = s[t] - mine;
    if (t == 255) cnt[0] = s[255];
}

__global__ void scatter_kernel(const int* __restrict__ span_ids, const int* __restrict__ masks,
                               const int* __restrict__ flag, const int* __restrict__ pooling,
                               const int* __restrict__ blockOff,
                               int* __restrict__ cS, int* __restrict__ cE,
                               int* __restrict__ cO, int* __restrict__ cI) {
    int bid = blockIdx.x, tid = threadIdx.x;
    int m = bid * 256 + tid;
    bool act = mask_at(masks, flag[0], m);
    unsigned long long b = __ballot(act);
    __shared__ int wA[4], wI[4];
    int lane = tid & 63, w = tid >> 6;
    int wAct = __popcll(b);
    if (lane == 0) { wA[w] = wAct; wI[w] = 64 - wAct; }
    __syncthreads();
    if (tid == 0) {
        int a = 0, ii = 0;
#pragma unroll
        for (int i = 0; i < 4; ++i) {
            int ca = wA[i], ci = wI[i];
            wA[i] = a; wI[i] = ii; a += ca; ii += ci;
        }
    }
    __syncthreads();
    unsigned long long below = (lane == 63) ? ~0ULL >> 1 : ((1ULL << lane) - 1ULL);
    if (act) {
        int rank = __popcll(b & below);
        int idx = blockOff[bid] + wA[w] + rank;
        int s = span_ids[2 * m], e = span_ids[2 * m + 1];
        int bb = m >> 14;
        int window = (pooling[0] != 0) ? 1 : 3;
        int cw = min(window, e - s);
        int base = (bb * 3 + (cw - 1)) * SEQ;
        cS[idx] = base + s;
        cE[idx] = base + (e - cw);
        cO[idx] = m;
    } else {
        int rank = __popcll(~b & below);
        int idx = (bid * 256 - blockOff[bid]) + wI[w] + rank;
        cI[idx] = m;
    }
}

__global__ void prep_wt_old_kernel(const float* __restrict__ W, bf16* __restrict__ Wt) {
    __shared__ float tile[64][65];
    int k0 = blockIdx.x * 64;
    int n0 = blockIdx.y * 64;
    int t = threadIdx.x;
    int c = t & 63, r4 = t >> 6;
    for (int r = r4; r < 64; r += 4)
        tile[r][c] = W[(size_t)(k0 + r) * HID + n0 + c];
    __syncthreads();
    for (int r = r4; r < 64; r += 4)
        Wt[(size_t)(n0 + r) * K2 + k0 + c] = __float2bfloat16(tile[c][r]);
}

__global__ __launch_bounds__(256, 4)
void span_gemm_old_kernel(const bf16* __restrict__ M3, const bf16* __restrict__ Wt,
                          const int* __restrict__ cS, const int* __restrict__ cE,
                          const int* __restrict__ cO, const int* __restrict__ cI,
                          const int* __restrict__ cnt,
                          const float* __restrict__ bias, float* __restrict__ out) {
    __shared__ char lA[128 * 128];
    __shared__ char lB[128 * 128];
    __shared__ int rS[128], rE[128], rO[128];

    const int tid = threadIdx.x;
    const int x = blockIdx.x;
    const int g = x & 7, j = x >> 3;
    const int mt = (j / 6) * 8 + g;
    const int ns = j % 6;
    const int n0 = ns * 128;

    const int count = cnt[0];
    const int actT = (count + 127) >> 7;

    if (mt >= actT) {
        int r = (mt - actT) * 128 + (tid >> 1);
        if (r < M_TOT - count) {
            int o = cI[r];
            const float* bsrc = bias + n0 + (tid & 1) * 64;
            float* dst = out + (size_t)o * HID + n0 + (tid & 1) * 64;
#pragma unroll
            for (int c = 0; c < 16; ++c)
                *(f32x4*)(dst + c * 4) = *(const f32x4*)(bsrc + c * 4);
        }
        return;
    }

    const int m0 = mt * 128;
    if (tid < 128) {
        int m = m0 + tid;
        rS[tid] = cS[m];
        rE[tid] = cE[m];
        rO[tid] = cO[m];
    }
    __syncthreads();

    const int lane = tid & 63, w = tid >> 6;
    const int wr = w >> 1, wc = w & 1;
    const int lr = lane & 15, lg = lane >> 4;
    const int lrow8 = lane >> 3;
    const int chunkp = ((lane & 7) ^ lrow8) << 4;

    const char* aPtr[2][4];
    const char* bPtr[4];
    int ldsOff[4];
#pragma unroll
    for (int it = 0; it < 4; ++it) {
        int i = it * 4 + w;
        int r = i * 8 + lrow8;
        aPtr[0][it] = (const char*)M3 + (size_t)rS[r] * (HID * 2) + chunkp;
        aPtr[1][it] = (const char*)M3 + (size_t)rE[r] * (HID * 2) + chunkp;
        bPtr[it]    = (const char*)Wt + (size_t)(n0 + r) * (K2 * 2) + chunkp;
        ldsOff[it]  = i * 1024;
    }

    f32x4 acc[4][4];
#pragma unroll
    for (int i = 0; i < 4; i++)
#pragma unroll
        for (int j2 = 0; j2 < 4; j2++) acc[i][j2] = (f32x4){0.f, 0.f, 0.f, 0.f};

    for (int kt = 0; kt < K2; kt += 64) {
        const int half = (kt >= HID) ? 1 : 0;
        const int colB = (kt - (half ? HID : 0)) * 2;
        const int ktB  = kt * 2;
        __syncthreads();
#pragma unroll
        for (int it = 0; it < 4; ++it)
            gll16(aPtr[half][it] + colB, lA + ldsOff[it]);
#pragma unroll
        for (int it = 0; it < 4; ++it)
            gll16(bPtr[it] + ktB, lB + ldsOff[it]);
        __syncthreads();
#pragma unroll
        for (int kk = 0; kk < 2; ++kk) {
            const int cb = kk * 4 + lg;
            s16x8 af[4], bfr[4];
#pragma unroll
            for (int i = 0; i < 4; ++i) {
                int row = wr * 64 + i * 16 + lr;
                af[i] = *(const s16x8*)(lA + row * 128 + ((cb ^ (row & 7)) << 4));
            }
#pragma unroll
            for (int j2 = 0; j2 < 4; ++j2) {
                int row = wc * 64 + j2 * 16 + lr;
                bfr[j2] = *(const s16x8*)(lB + row * 128 + ((cb ^ (row & 7)) << 4));
            }
#pragma unroll
            for (int i = 0; i < 4; ++i)
#pragma unroll
                for (int j2 = 0; j2 < 4; ++j2)
                    acc[i][j2] = __builtin_amdgcn_mfma_f32_16x16x32_bf16(af[i], bfr[j2], acc[i][j2], 0, 0, 0);
        }
    }

#pragma unroll
    for (int i = 0; i < 4; i++) {
#pragma unroll
        for (int j2 = 0; j2 < 4; j2++) {
#pragma unroll
            for (int q = 0; q < 4; q++) {
                int mloc = wr * 64 + i * 16 + lg * 4 + q;
                int o = rO[mloc];
                if (o >= 0) {
                    int n = n0 + wc * 64 + j2 * 16 + lr;
                    out[(size_t)o * HID + n] = acc[i][j2][q] + bias[n];
                }
            }
        }
    }
}

// ---------------------------------------------------------------------------
extern "C" void kernel_launch(void* const* d_in, const int* in_sizes, int n_in,
                              void* d_out, int out_size, void* d_ws, size_t ws_size,
                              hipStream_t stream) {
    const float* token_reps = (const float*)d_in[0];
    const int*   span_ids   = (const int*)d_in[1];
    const int*   span_masks = (const int*)d_in[2];
    const int*   pooling    = (const int*)d_in[3];
    const float* W          = (const float*)d_in[4];
    const float* bias       = (const float*)d_in[5];
    float* out = (float*)d_out;

    char* ws = (char*)d_ws;
    int*  flag = (int*)ws;

    const size_t M3_OFF   = (size_t)2 << 20;
    const size_t M3_BYTES = (size_t)MROWS * HID * 2;          // 37,748,736
    bf16* M3 = (bf16*)(ws + M3_OFF);

    // new-path layout: M3 | Wt2 (1536x768 bf16) | P (24576x1536 bf16)
    const size_t WT2_OFF  = M3_OFF + M3_BYTES;
    const size_t WT2_BYTES = (size_t)K2 * HID * 2;            // 2,359,296
    const size_t P_OFF    = WT2_OFF + WT2_BYTES;
    const size_t P_BYTES  = (size_t)MROWS * K2 * 2;           // 75,497,472
    const size_t NEED_NEW = P_OFF + P_BYTES;                  // ~117.7 MB

    hipMemsetAsync(ws, 0, 64, stream);
    mask_detect_kernel<<<64, 256, 0, stream>>>((const unsigned*)span_masks, flag);
    prep_m3_kernel<<<dim3(SEQ / 16, NB), 256, 0, stream>>>(token_reps, M3);

    if (ws_size >= NEED_NEW) {
        bf16* Wt2 = (bf16*)(ws + WT2_OFF);
        bf16* P   = (bf16*)(ws + P_OFF);
        prep_wt2_kernel<<<dim3(HID / 64, K2 / 64), 256, 0, stream>>>(W, Wt2);
        dense_gemm_kernel<<<NWG_NEW, 512, 0, stream>>>(M3, Wt2, P);
        epilogue_kernel<<<2048, 256, 0, stream>>>(P, span_ids, span_masks, flag,
                                                  pooling, bias, out);
    } else {
        // fallback: R8's compacted gathered GEMM (fits in ~42 MB of ws)
        int* cnt      = (int*)(ws + 4);
        int* blockCnt = (int*)(ws + 1024);
        int* blockOff = (int*)(ws + 2048);
        int* cS = (int*)(ws + 4096);
        int* cE = (int*)(ws + 4096 + 4 * (size_t)CMP_CAP);
        int* cO = (int*)(ws + 4096 + 8 * (size_t)CMP_CAP);
        int* cI = (int*)(ws + 4096 + 12 * (size_t)CMP_CAP);
        bf16* WtOld = (bf16*)(ws + WT2_OFF);   // K2-stride Wt, 2.25 MB
        init_compact_kernel<<<(CMP_CAP + 255) / 256, 256, 0, stream>>>(cS, cE, cO);
        count_kernel<<<M_TOT / 256, 256, 0, stream>>>(span_masks, flag, blockCnt);
        scan_kernel<<<1, 256, 0, stream>>>(blockCnt, blockOff, cnt);
        scatter_kernel<<<M_TOT / 256, 256, 0, stream>>>(span_ids, span_masks, flag,
                                                        pooling, blockOff, cS, cE, cO, cI);
        prep_wt_old_kernel<<<dim3(K2 / 64, HID / 64), 256, 0, stream>>>(W, WtOld);
        span_gemm_old_kernel<<<NWG_OLD, 256, 0, stream>>>(
            M3, WtOld, cS, cE, cO, cI, cnt, bias, out);
    }
}

// Round 11
// 148.281 us; speedup vs baseline: 1.0782x; 1.0782x over previous
//
#include <hip/hip_runtime.h>
#include <hip/hip_bf16.h>

// Problem constants (fixed by setup_inputs)
#define NB 4
#define SEQ 2048
#define HID 768
#define NSPAN 16384            // spans per batch
#define M_TOT (NB * NSPAN)     // 65536 rows
#define K2 1536                // 2*HID
#define MROWS (NB * 3 * SEQ)   // 24576 table rows (batch x width-class x pos)
// old (fallback) path constants
#define CMP_CAP 66560
#define MT_TOT 520
#define NWG_OLD (MT_TOT * 6)
// new path GEMM grid: 192 m-tiles x 12 n-strips
#define NWG_NEW 2304

typedef float f32x4 __attribute__((ext_vector_type(4)));
typedef short s16x8 __attribute__((ext_vector_type(8)));
typedef unsigned short u16x4 __attribute__((ext_vector_type(4)));
using bf16 = __hip_bfloat16;

__device__ __forceinline__ void gll16(const void* g, void* l) {
    __builtin_amdgcn_global_load_lds(
        (const __attribute__((address_space(1))) unsigned*)g,
        (__attribute__((address_space(3))) unsigned*)l, 16, 0, 0);
}

__device__ __forceinline__ float bf2f(unsigned short v) {
    union { unsigned u; float f; } cv; cv.u = ((unsigned)v) << 16; return cv.f;
}

// ---------------------------------------------------------------------------
__global__ void mask_detect_kernel(const unsigned* __restrict__ masks, int* __restrict__ flag) {
    int t = blockIdx.x * 256 + threadIdx.x;
    if (t < 16384) {
        unsigned v = masks[t];
        if (v > 1u) atomicOr(flag, 1);   // multi-byte pattern => byte-packed bools
    }
}

__device__ __forceinline__ bool mask_at(const int* masks, int u8, int m) {
    return u8 ? (((const unsigned char*)masks)[m] != 0) : (masks[m] != 0);
}

// ---------------------------------------------------------------------------
// M3[b][c][p][h] = max over T[b, p .. p+c] (c = 0,1,2 => window 1,2,3), bf16.
__global__ void prep_m3_kernel(const float* __restrict__ T, bf16* __restrict__ M3) {
    int b = blockIdx.y;
    int p0 = blockIdx.x * 16;
    int t = threadIdx.x;   // 256
    const float* Tb = T + (size_t)b * SEQ * HID;
    bf16* o0 = M3 + (size_t)(b * 3 + 0) * SEQ * HID;
    bf16* o1 = M3 + (size_t)(b * 3 + 1) * SEQ * HID;
    bf16* o2 = M3 + (size_t)(b * 3 + 2) * SEQ * HID;
#pragma unroll
    for (int c = 0; c < 3; ++c) {
        int h = t + c * 256;
        float x0 = Tb[(size_t)p0 * HID + h];
        float x1 = Tb[(size_t)min(p0 + 1, SEQ - 1) * HID + h];
        for (int i = 0; i < 16; ++i) {
            int p = p0 + i;
            float x2 = Tb[(size_t)min(p + 2, SEQ - 1) * HID + h];
            float m2 = fmaxf(x0, x1);
            float m3v = fmaxf(m2, x2);
            size_t off = (size_t)p * HID + h;
            o0[off] = __float2bfloat16(x0);
            o1[off] = __float2bfloat16(m2);
            o2[off] = __float2bfloat16(m3v);
            x0 = x1; x1 = x2;
        }
    }
}

// ===========================================================================
// NEW PATH: dense table GEMM + gather-add epilogue
// ===========================================================================

// Wt2[n'][k'] (n' 0..1535, k' 0..767):
//   n'<768:  W[k'][n']         (start half, W rows 0..767)
//   n'>=768: W[768+k'][n'-768] (end half,  W rows 768..1535)
__global__ void prep_wt2_kernel(const float* __restrict__ W, bf16* __restrict__ Wt) {
    __shared__ float tile[64][65];
    int k0 = blockIdx.x * 64;          // 12 blocks
    int n0 = blockIdx.y * 64;          // 24 blocks
    int half = (n0 >= HID) ? 1 : 0;
    int nn = n0 - half * HID;
    int t = threadIdx.x;
    int c = t & 63, r4 = t >> 6;
    for (int r = r4; r < 64; r += 4)
        tile[r][c] = W[(size_t)(half * HID + k0 + r) * HID + nn + c];
    __syncthreads();
    for (int r = r4; r < 64; r += 4)
        Wt[(size_t)(n0 + r) * HID + k0 + c] = __float2bfloat16(tile[c][r]);
}

// Dense GEMM: P[r][n'] = sum_k M3[r][k] * Wt2[n'][k], r<24576, n'<1536.
// R5/R8's proven 2-barrier 128x128 structure; A rows are SEQUENTIAL (no
// gather). chunk^=row&7 swizzle on source AND read (measured 0 conflicts).
// XCD co-location: all 12 n-strips of one m-tile on one XCD, m-tiles
// round-robin across XCDs (balanced, bijective).
__global__ __launch_bounds__(256, 4)
void dense_gemm_kernel(const bf16* __restrict__ M3, const bf16* __restrict__ Wt,
                       bf16* __restrict__ P) {
    __shared__ char lA[16384];
    __shared__ char lB[16384];

    const int tid = threadIdx.x;
    const int x = blockIdx.x;
    const int g = x & 7, j = x >> 3;
    const int mt = (j / 12) * 8 + g;   // 0..191
    const int ns = j % 12;             // 0..11
    const int m0 = mt * 128, n0 = ns * 128;

    const int lane = tid & 63, w = tid >> 6;
    const int wr = w >> 1, wc = w & 1;
    const int lr = lane & 15, lg = lane >> 4;
    const int lrow8 = lane >> 3;
    const int chunkp = ((lane & 7) ^ lrow8) << 4;

    const char* aPtr[4];
    const char* bPtr[4];
    int ldsOff[4];
#pragma unroll
    for (int it = 0; it < 4; ++it) {
        int i = it * 4 + w;                    // 1KB-issue index 0..15
        int r = i * 8 + lrow8;                 // LDS row 0..127
        aPtr[it] = (const char*)M3 + (size_t)(m0 + r) * (HID * 2) + chunkp;
        bPtr[it] = (const char*)Wt + (size_t)(n0 + r) * (HID * 2) + chunkp;
        ldsOff[it] = i * 1024;
    }

    f32x4 acc[4][4];
#pragma unroll
    for (int i = 0; i < 4; i++)
#pragma unroll
        for (int j2 = 0; j2 < 4; j2++) acc[i][j2] = (f32x4){0.f, 0.f, 0.f, 0.f};

    for (int kt = 0; kt < HID; kt += 64) {
        const int colB = kt * 2;
        __syncthreads();
#pragma unroll
        for (int it = 0; it < 4; ++it)
            gll16(aPtr[it] + colB, lA + ldsOff[it]);
#pragma unroll
        for (int it = 0; it < 4; ++it)
            gll16(bPtr[it] + colB, lB + ldsOff[it]);
        __syncthreads();
#pragma unroll
        for (int kk = 0; kk < 2; ++kk) {
            const int cb = kk * 4 + lg;
            s16x8 af[4], bfr[4];
#pragma unroll
            for (int i = 0; i < 4; ++i) {
                int row = wr * 64 + i * 16 + lr;
                af[i] = *(const s16x8*)(lA + row * 128 + ((cb ^ (row & 7)) << 4));
            }
#pragma unroll
            for (int j2 = 0; j2 < 4; ++j2) {
                int row = wc * 64 + j2 * 16 + lr;
                bfr[j2] = *(const s16x8*)(lB + row * 128 + ((cb ^ (row & 7)) << 4));
            }
#pragma unroll
            for (int i = 0; i < 4; ++i)
#pragma unroll
                for (int j2 = 0; j2 < 4; ++j2)
                    acc[i][j2] = __builtin_amdgcn_mfma_f32_16x16x32_bf16(af[i], bfr[j2], acc[i][j2], 0, 0, 0);
        }
    }

    // C/D layout (verified m89): col = lane&15, row = (lane>>4)*4 + q
    unsigned short* Pu = (unsigned short*)P;
#pragma unroll
    for (int i = 0; i < 4; i++) {
#pragma unroll
        for (int j2 = 0; j2 < 4; j2++) {
#pragma unroll
            for (int q = 0; q < 4; q++) {
                int prow = m0 + wr * 64 + i * 16 + lg * 4 + q;
                int pcol = n0 + wc * 64 + j2 * 16 + lr;
                bf16 v = __float2bfloat16(acc[i][j2][q]);
                Pu[(size_t)prow * K2 + pcol] = *(unsigned short*)&v;
            }
        }
    }
}

// out[m] = mask ? P[rS][0:768] + P[rE][768:1536] + bias : bias
// One wave per row; 3 rounds of (lane x 4 els): 8B bf16 loads, 16B f32 store.
__global__ __launch_bounds__(256)
void epilogue_kernel(const bf16* __restrict__ P, const int* __restrict__ span_ids,
                     const int* __restrict__ masks, const int* __restrict__ flag,
                     const int* __restrict__ pooling, const float* __restrict__ bias,
                     float* __restrict__ out) {
    int gw = (blockIdx.x * 256 + threadIdx.x) >> 6;   // 0..8191
    int lane = threadIdx.x & 63;
    int u8 = flag[0];
    int window = (pooling[0] != 0) ? 1 : 3;
    const unsigned short* Pu = (const unsigned short*)P;
    for (int m = gw; m < M_TOT; m += 8192) {
        float* orow = out + (size_t)m * HID;
        if (!mask_at(masks, u8, m)) {
#pragma unroll
            for (int rnd = 0; rnd < 3; ++rnd) {
                int n = rnd * 256 + lane * 4;
                *(f32x4*)(orow + n) = *(const f32x4*)(bias + n);
            }
            continue;
        }
        int s = span_ids[2 * m], e = span_ids[2 * m + 1];
        int b = m >> 14;
        int cw = min(window, e - s);           // e-s >= 1 always
        int base = (b * 3 + (cw - 1)) * SEQ;
        const unsigned short* ps = Pu + (size_t)(base + s) * K2;
        const unsigned short* pe = Pu + (size_t)(base + e - cw) * K2 + HID;
#pragma unroll
        for (int rnd = 0; rnd < 3; ++rnd) {
            int n = rnd * 256 + lane * 4;
            u16x4 a = *(const u16x4*)(ps + n);
            u16x4 c = *(const u16x4*)(pe + n);
            f32x4 bb = *(const f32x4*)(bias + n);
            f32x4 r;
#pragma unroll
            for (int k = 0; k < 4; ++k) r[k] = bf2f(a[k]) + bf2f(c[k]) + bb[k];
            *(f32x4*)(orow + n) = r;
        }
    }
}

// ===========================================================================
// OLD PATH (fallback if ws_size too small): R8's compacted gathered GEMM
// ===========================================================================

__global__ void init_compact_kernel(int* __restrict__ cS, int* __restrict__ cE,
                                    int* __restrict__ cO) {
    int i = blockIdx.x * 256 + threadIdx.x;
    if (i < CMP_CAP) { cS[i] = 0; cE[i] = 0; cO[i] = -1; }
}

__global__ void count_kernel(const int* __restrict__ masks, const int* __restrict__ flag,
                             int* __restrict__ blockCnt) {
    int bid = blockIdx.x, tid = threadIdx.x;
    bool act = mask_at(masks, flag[0], bid * 256 + tid);
    unsigned long long b = __ballot(act);
    __shared__ int wc[4];
    if ((tid & 63) == 0) wc[tid >> 6] = __popcll(b);
    __syncthreads();
    if (tid == 0) blockCnt[bid] = wc[0] + wc[1] + wc[2] + wc[3];
}

__global__ void scan_kernel(const int* __restrict__ blockCnt, int* __restrict__ blockOff,
                            int* __restrict__ cnt) {
    __shared__ int s[256];
    int t = threadIdx.x;
    int mine = blockCnt[t];
    s[t] = mine;
    __syncthreads();
    for (int d = 1; d < 256; d <<= 1) {
        int v = (t >= d) ? s[t - d] : 0;
        __syncthreads();
        s[t] += v;
        __syncthreads();
    }
    blockOff[t] = s[t] - mine;
    if (t == 255) cnt[0] = s[255];
}

__global__ void scatter_kernel(const int* __restrict__ span_ids, const int* __restrict__ masks,
                               const int* __restrict__ flag, const int* __restrict__ pooling,
                               const int* __restrict__ blockOff,
                               int* __restrict__ cS, int* __restrict__ cE,
                               int* __restrict__ cO, int* __restrict__ cI) {
    int bid = blockIdx.x, tid = threadIdx.x;
    int m = bid * 256 + tid;
    bool act = mask_at(masks, flag[0], m);
    unsigned long long b = __ballot(act);
    __shared__ int wA[4], wI[4];
    int lane = tid & 63, w = tid >> 6;
    int wAct = __popcll(b);
    if (lane == 0) { wA[w] = wAct; wI[w] = 64 - wAct; }
    __syncthreads();
    if (tid == 0) {
        int a = 0, ii = 0;
#pragma unroll
        for (int i = 0; i < 4; ++i) {
            int ca = wA[i], ci = wI[i];
            wA[i] = a; wI[i] = ii; a += ca; ii += ci;
        }
    }
    __syncthreads();
    unsigned long long below = (lane == 63) ? ~0ULL >> 1 : ((1ULL << lane) - 1ULL);
    if (act) {
        int rank = __popcll(b & below);
        int idx = blockOff[bid] + wA[w] + rank;
        int s = span_ids[2 * m], e = span_ids[2 * m + 1];
        int bb = m >> 14;
        int window = (pooling[0] != 0) ? 1 : 3;
        int cw = min(window, e - s);
        int base = (bb * 3 + (cw - 1)) * SEQ;
        cS[idx] = base + s;
        cE[idx] = base + (e - cw);
        cO[idx] = m;
    } else {
        int rank = __popcll(~b & below);
        int idx = (bid * 256 - blockOff[bid]) + wI[w] + rank;
        cI[idx] = m;
    }
}

__global__ void prep_wt_old_kernel(const float* __restrict__ W, bf16* __restrict__ Wt) {
    __shared__ float tile[64][65];
    int k0 = blockIdx.x * 64;
    int n0 = blockIdx.y * 64;
    int t = threadIdx.x;
    int c = t & 63, r4 = t >> 6;
    for (int r = r4; r < 64; r += 4)
        tile[r][c] = W[(size_t)(k0 + r) * HID + n0 + c];
    __syncthreads();
    for (int r = r4; r < 64; r += 4)
        Wt[(size_t)(n0 + r) * K2 + k0 + c] = __float2bfloat16(tile[c][r]);
}

__global__ __launch_bounds__(256, 4)
void span_gemm_old_kernel(const bf16* __restrict__ M3, const bf16* __restrict__ Wt,
                          const int* __restrict__ cS, const int* __restrict__ cE,
                          const int* __restrict__ cO, const int* __restrict__ cI,
                          const int* __restrict__ cnt,
                          const float* __restrict__ bias, float* __restrict__ out) {
    __shared__ char lA[128 * 128];
    __shared__ char lB[128 * 128];
    __shared__ int rS[128], rE[128], rO[128];

    const int tid = threadIdx.x;
    const int x = blockIdx.x;
    const int g = x & 7, j = x >> 3;
    const int mt = (j / 6) * 8 + g;
    const int ns = j % 6;
    const int n0 = ns * 128;

    const int count = cnt[0];
    const int actT = (count + 127) >> 7;

    if (mt >= actT) {
        int r = (mt - actT) * 128 + (tid >> 1);
        if (r < M_TOT - count) {
            int o = cI[r];
            const float* bsrc = bias + n0 + (tid & 1) * 64;
            float* dst = out + (size_t)o * HID + n0 + (tid & 1) * 64;
#pragma unroll
            for (int c = 0; c < 16; ++c)
                *(f32x4*)(dst + c * 4) = *(const f32x4*)(bsrc + c * 4);
        }
        return;
    }

    const int m0 = mt * 128;
    if (tid < 128) {
        int m = m0 + tid;
        rS[tid] = cS[m];
        rE[tid] = cE[m];
        rO[tid] = cO[m];
    }
    __syncthreads();

    const int lane = tid & 63, w = tid >> 6;
    const int wr = w >> 1, wc = w & 1;
    const int lr = lane & 15, lg = lane >> 4;
    const int lrow8 = lane >> 3;
    const int chunkp = ((lane & 7) ^ lrow8) << 4;

    const char* aPtr[2][4];
    const char* bPtr[4];
    int ldsOff[4];
#pragma unroll
    for (int it = 0; it < 4; ++it) {
        int i = it * 4 + w;
        int r = i * 8 + lrow8;
        aPtr[0][it] = (const char*)M3 + (size_t)rS[r] * (HID * 2) + chunkp;
        aPtr[1][it] = (const char*)M3 + (size_t)rE[r] * (HID * 2) + chunkp;
        bPtr[it]    = (const char*)Wt + (size_t)(n0 + r) * (K2 * 2) + chunkp;
        ldsOff[it]  = i * 1024;
    }

    f32x4 acc[4][4];
#pragma unroll
    for (int i = 0; i < 4; i++)
#pragma unroll
        for (int j2 = 0; j2 < 4; j2++) acc[i][j2] = (f32x4){0.f, 0.f, 0.f, 0.f};

    for (int kt = 0; kt < K2; kt += 64) {
        const int half = (kt >= HID) ? 1 : 0;
        const int colB = (kt - (half ? HID : 0)) * 2;
        const int ktB  = kt * 2;
        __syncthreads();
#pragma unroll
        for (int it = 0; it < 4; ++it)
            gll16(aPtr[half][it] + colB, lA + ldsOff[it]);
#pragma unroll
        for (int it = 0; it < 4; ++it)
            gll16(bPtr[it] + ktB, lB + ldsOff[it]);
        __syncthreads();
#pragma unroll
        for (int kk = 0; kk < 2; ++kk) {
            const int cb = kk * 4 + lg;
            s16x8 af[4], bfr[4];
#pragma unroll
            for (int i = 0; i < 4; ++i) {
                int row = wr * 64 + i * 16 + lr;
                af[i] = *(const s16x8*)(lA + row * 128 + ((cb ^ (row & 7)) << 4));
            }
#pragma unroll
            for (int j2 = 0; j2 < 4; ++j2) {
                int row = wc * 64 + j2 * 16 + lr;
                bfr[j2] = *(const s16x8*)(lB + row * 128 + ((cb ^ (row & 7)) << 4));
            }
#pragma unroll
            for (int i = 0; i < 4; ++i)
#pragma unroll
                for (int j2 = 0; j2 < 4; ++j2)
                    acc[i][j2] = __builtin_amdgcn_mfma_f32_16x16x32_bf16(af[i], bfr[j2], acc[i][j2], 0, 0, 0);
        }
    }

#pragma unroll
    for (int i = 0; i < 4; i++) {
#pragma unroll
        for (int j2 = 0; j2 < 4; j2++) {
#pragma unroll
            for (int q = 0; q < 4; q++) {
                int mloc = wr * 64 + i * 16 + lg * 4 + q;
                int o = rO[mloc];
                if (o >= 0) {
                    int n = n0 + wc * 64 + j2 * 16 + lr;
                    out[(size_t)o * HID + n] = acc[i][j2][q] + bias[n];
                }
            }
        }
    }
}

// ---------------------------------------------------------------------------
extern "C" void kernel_launch(void* const* d_in, const int* in_sizes, int n_in,
                              void* d_out, int out_size, void* d_ws, size_t ws_size,
                              hipStream_t stream) {
    const float* token_reps = (const float*)d_in[0];
    const int*   span_ids   = (const int*)d_in[1];
    const int*   span_masks = (const int*)d_in[2];
    const int*   pooling    = (const int*)d_in[3];
    const float* W          = (const float*)d_in[4];
    const float* bias       = (const float*)d_in[5];
    float* out = (float*)d_out;

    char* ws = (char*)d_ws;
    int*  flag = (int*)ws;

    const size_t M3_OFF   = (size_t)2 << 20;
    const size_t M3_BYTES = (size_t)MROWS * HID * 2;          // 37,748,736
    bf16* M3 = (bf16*)(ws + M3_OFF);

    // new-path layout: M3 | Wt2 (1536x768 bf16) | P (24576x1536 bf16)
    const size_t WT2_OFF  = M3_OFF + M3_BYTES;
    const size_t WT2_BYTES = (size_t)K2 * HID * 2;            // 2,359,296
    const size_t P_OFF    = WT2_OFF + WT2_BYTES;
    const size_t P_BYTES  = (size_t)MROWS * K2 * 2;           // 75,497,472
    const size_t NEED_NEW = P_OFF + P_BYTES;                  // ~117.7 MB

    hipMemsetAsync(ws, 0, 64, stream);
    mask_detect_kernel<<<64, 256, 0, stream>>>((const unsigned*)span_masks, flag);

    if (ws_size >= NEED_NEW) {
        bf16* Wt2 = (bf16*)(ws + WT2_OFF);
        bf16* P   = (bf16*)(ws + P_OFF);
        prep_wt2_kernel<<<dim3(HID / 64, K2 / 64), 256, 0, stream>>>(W, Wt2);
        prep_m3_kernel<<<dim3(SEQ / 16, NB), 256, 0, stream>>>(token_reps, M3);
        dense_gemm_kernel<<<NWG_NEW, 256, 0, stream>>>(M3, Wt2, P);
        epilogue_kernel<<<2048, 256, 0, stream>>>(P, span_ids, span_masks, flag,
                                                  pooling, bias, out);
    } else {
        // fallback: R8's compacted gathered GEMM (fits in ~42 MB of ws)
        int* cnt      = (int*)(ws + 4);
        int* blockCnt = (int*)(ws + 1024);
        int* blockOff = (int*)(ws + 2048);
        int* cS = (int*)(ws + 4096);
        int* cE = (int*)(ws + 4096 + 4 * (size_t)CMP_CAP);
        int* cO = (int*)(ws + 4096 + 8 * (size_t)CMP_CAP);
        int* cI = (int*)(ws + 4096 + 12 * (size_t)CMP_CAP);
        bf16* WtOld = (bf16*)(ws + WT2_OFF);   // K2-stride Wt, 2.25 MB
        prep_m3_kernel<<<dim3(SEQ / 16, NB), 256, 0, stream>>>(token_reps, M3);
        init_compact_kernel<<<(CMP_CAP + 255) / 256, 256, 0, stream>>>(cS, cE, cO);
        count_kernel<<<M_TOT / 256, 256, 0, stream>>>(span_masks, flag, blockCnt);
        scan_kernel<<<1, 256, 0, stream>>>(blockCnt, blockOff, cnt);
        scatter_kernel<<<M_TOT / 256, 256, 0, stream>>>(span_ids, span_masks, flag,
                                                        pooling, blockOff, cS, cE, cO, cI);
        prep_wt_old_kernel<<<dim3(K2 / 64, HID / 64), 256, 0, stream>>>(W, WtOld);
        span_gemm_old_kernel<<<NWG_OLD, 256, 0, stream>>>(
            M3, WtOld, cS, cE, cO, cI, cnt, bias, out);
    }
}